// Round 1
// baseline (1674.534 us; speedup 1.0000x reference)
//
#include <hip/hip_runtime.h>

typedef __attribute__((ext_vector_type(8))) short bf16x8;
typedef __attribute__((ext_vector_type(4))) float f32x4;
typedef __attribute__((ext_vector_type(2))) _Float16 f16x2;

#define MFMA(a, b, c) __builtin_amdgcn_mfma_f32_16x16x32_bf16((a), (b), (c), 0, 0, 0)

__device__ __forceinline__ unsigned short f2bf(float f) {
    unsigned int u = __builtin_bit_cast(unsigned int, f);
    return (unsigned short)((u + 0x7FFFu + ((u >> 16) & 1u)) >> 16);  // RNE
}

// B=512, S=128, I=64, H=256, C=10
// grid 256 blocks (2 batch rows each), 512 threads (8 waves), 1 block/CU.
__global__ __launch_bounds__(512, 2) void ltc_kernel(
    const float* __restrict__ x, const float* __restrict__ W_gd,
    const float* __restrict__ b_gd, const float* __restrict__ W_tau,
    const float* __restrict__ b_tau, const float* __restrict__ gleak,
    const float* __restrict__ cm, const float* __restrict__ W_fc,
    const float* __restrict__ b_fc, float* __restrict__ out)
{
    const int tid  = threadIdx.x;
    const int lane = tid & 63;
    const int wv   = tid >> 6;          // wave 0..7, owns hidden units [32*wv, 32*wv+32)
    const int c16  = lane & 15;
    const int kg   = lane >> 4;         // k-group (8 contiguous k per lane)
    const int row0 = blockIdx.x * 2;    // global batch rows row0, row0+1

    __shared__ __align__(16) unsigned short abuf[2][264];   // h_eff bf16 (stride 264 for bank spread)
    __shared__ __align__(16) unsigned short xbuf[2][72];    // x_t bf16
    __shared__ __align__(16) unsigned short wxl[512][72];   // W_gd x-part bf16 (73.7 KB)
    __shared__ float hout[2][257];

    // ---- stage x-part of W_gd into LDS (bf16), zero h buffer ----
    for (int idx = tid; idx < 512 * 64; idx += 512) {
        int j = idx >> 6, i = idx & 63;
        wxl[j][i] = f2bf(W_gd[j * 320 + i]);
    }
    for (int idx = tid; idx < 2 * 264; idx += 512) ((unsigned short*)abuf)[idx] = 0;

    // ---- recurrent weights (h-part of W_gd + W_tau) into registers, bf16 ----
    // tiles: 0:gate[uA] 1:gate[uB] 2:dyn[uA] 3:dyn[uB] 4:tau[uA] 5:tau[uB]
    const int uA = 32 * wv + c16;
    const int uB = uA + 16;
    bf16x8 Wr[6][8];
    {
        const int wrow[6] = { uA, uB, 256 + uA, 256 + uB, uA, uB };
        #pragma unroll
        for (int t = 0; t < 6; ++t) {
            const float* src = (t < 4) ? (W_gd + wrow[t] * 320 + 64)
                                       : (W_tau + wrow[t] * 256);
            #pragma unroll
            for (int s = 0; s < 8; ++s) {
                const float4* p = (const float4*)(src + s * 32 + kg * 8);
                float4 a = p[0], b = p[1];
                bf16x8 v;
                v[0] = (short)f2bf(a.x); v[1] = (short)f2bf(a.y);
                v[2] = (short)f2bf(a.z); v[3] = (short)f2bf(a.w);
                v[4] = (short)f2bf(b.x); v[5] = (short)f2bf(b.y);
                v[6] = (short)f2bf(b.z); v[7] = (short)f2bf(b.w);
                Wr[t][s] = v;
            }
        }
    }

    // per-lane constants (meaningful for lane<16; others compute discarded garbage)
    const float btau0 = b_tau[uA], btau1 = b_tau[uB];
    const float cden0 = __logf(1.f + __expf(cm[uA])) + __logf(1.f + __expf(gleak[uA])) + 1e-6f;
    const float cden1 = __logf(1.f + __expf(cm[uB])) + __logf(1.f + __expf(gleak[uB])) + 1e-6f;
    float bgd[4] = { b_gd[uA], b_gd[uB], b_gd[256 + uA], b_gd[256 + uB] };

    // A-operand LDS pointers; pad rows (c16>=2) broadcast-read row 0 (harmless:
    // MFMA output row r depends only on A row r; rows >=2 are never consumed)
    const int rsel = (c16 < 2) ? c16 : 0;
    const unsigned short* aptr = &abuf[rsel][kg * 8];
    const unsigned short* xptr = &xbuf[rsel][kg * 8];

    // RK state, fragment layout: lane<16 holds rows 0,1 (regs 0,1), col = lane
    float hv[2][2] = {{0.f, 0.f}, {0.f, 0.f}};
    f16x2 zh; zh[0] = (_Float16)0.f; zh[1] = (_Float16)0.f;
    f16x2 kk1[2] = { zh, zh }, kk2[2] = { zh, zh }, kk3[2] = { zh, zh };

    __syncthreads();

    #pragma unroll 1
    for (int ts = 0; ts < 128; ++ts) {
        // ---- stage x_t ----
        if (tid < 128) {
            int r = tid >> 6, i = tid & 63;
            xbuf[r][i] = f2bf(x[((row0 + r) * 128 + ts) * 64 + i]);
        }
        __syncthreads();

        // ---- x-part GEMM (once per step, reused by all 4 RK stages) ----
        f32x4 gx[4];
        #pragma unroll
        for (int t = 0; t < 4; ++t) gx[t] = (f32x4){0.f, 0.f, 0.f, 0.f};
        {
            const int xrow[4] = { uA, uB, 256 + uA, 256 + uB };
            #pragma unroll
            for (int s = 0; s < 2; ++s) {
                bf16x8 ax = *(const bf16x8*)(xptr + s * 32);
                #pragma unroll
                for (int t = 0; t < 4; ++t) {
                    bf16x8 bx = *(const bf16x8*)(&wxl[xrow[t]][kg * 8 + s * 32]);
                    gx[t] = MFMA(ax, bx, gx[t]);
                }
            }
        }
        f16x2 gdx[4];
        #pragma unroll
        for (int t = 0; t < 4; ++t) {
            gdx[t][0] = (_Float16)(gx[t][0] + bgd[t]);
            gdx[t][1] = (_Float16)(gx[t][1] + bgd[t]);
        }

        // ---- 4 RK stages (3/8-rule) ----
        #pragma unroll
        for (int stg = 0; stg < 4; ++stg) {
            // tau matmul first (releases its accs before gate/dyn)
            f32x4 aT0 = {0.f, 0.f, 0.f, 0.f}, aT1 = {0.f, 0.f, 0.f, 0.f};
            #pragma unroll
            for (int s = 0; s < 8; ++s) {
                bf16x8 A = *(const bf16x8*)(aptr + s * 32);
                aT0 = MFMA(A, Wr[4][s], aT0);
                aT1 = MFMA(A, Wr[5][s], aT1);
            }
            float den[2][2];
            den[0][0] = __logf(1.f + __expf(aT0[0] + btau0)) + cden0;
            den[0][1] = __logf(1.f + __expf(aT0[1] + btau0)) + cden0;
            den[1][0] = __logf(1.f + __expf(aT1[0] + btau1)) + cden1;
            den[1][1] = __logf(1.f + __expf(aT1[1] + btau1)) + cden1;

            // gate/dyn matmul
            f32x4 g[4];
            #pragma unroll
            for (int t = 0; t < 4; ++t) g[t] = (f32x4){0.f, 0.f, 0.f, 0.f};
            #pragma unroll
            for (int s = 0; s < 8; ++s) {
                bf16x8 A = *(const bf16x8*)(aptr + s * 32);
                #pragma unroll
                for (int t = 0; t < 4; ++t) g[t] = MFMA(A, Wr[t][s], g[t]);
            }
            __syncthreads();   // all abuf reads of this stage are done

            // elementwise dhdt + RK bookkeeping (4 real slots/lane: 2 units x 2 rows)
            #pragma unroll
            for (int ti = 0; ti < 2; ++ti) {
                #pragma unroll
                for (int r = 0; r < 2; ++r) {
                    float gate = g[ti][r]     + (float)gdx[ti][r];
                    float dyn  = g[2 + ti][r] + (float)gdx[2 + ti][r];
                    float sig = __fdividef(1.f, 1.f + __expf(-gate));
                    float th  = 1.f - __fdividef(2.f, __expf(2.f * dyn) + 1.f);
                    float k1v = (float)kk1[ti][r];
                    float k2v = (float)kk2[ti][r];
                    float k3v = (float)kk3[ti][r];
                    float h0 = hv[ti][r];
                    float ec;                      // dhdt argument of this stage
                    if      (stg == 0) ec = h0;
                    else if (stg == 1) ec = h0 + k1v * (1.f / 3.f);
                    else if (stg == 2) ec = h0 - k1v * (1.f / 3.f) + k2v;
                    else               ec = h0 + k1v - k2v + k3v;
                    float kv = __fdividef(sig * th - ec, den[ti][r]);
                    float en;
                    if (stg == 0)      { kk1[ti][r] = (_Float16)kv; en = h0 + kv * (1.f / 3.f); }
                    else if (stg == 1) { kk2[ti][r] = (_Float16)kv; en = h0 - k1v * (1.f / 3.f) + kv; }
                    else if (stg == 2) { kk3[ti][r] = (_Float16)kv; en = h0 + k1v - k2v + kv; }
                    else               { en = h0 + 0.125f * (k1v + 3.f * (k2v + k3v) + kv); hv[ti][r] = en; }
                    if (lane < 16) {
                        int u = (ti == 0) ? uA : uB;
                        abuf[r][u] = f2bf(en);
                    }
                }
            }
            __syncthreads();   // writes visible before next stage's reads
        }
    }

    // ---- epilogue: out = h @ W_fc^T + b_fc ----
    if (lane < 16) {
        hout[0][uA] = hv[0][0]; hout[1][uA] = hv[0][1];
        hout[0][uB] = hv[1][0]; hout[1][uB] = hv[1][1];
    }
    __syncthreads();
    if (tid < 20) {
        int r = tid / 10, c = tid % 10;
        float acc = b_fc[c];
        for (int k = 0; k < 256; ++k) acc = fmaf(hout[r][k], W_fc[c * 256 + k], acc);
        out[(row0 + r) * 10 + c] = acc;
    }
}

extern "C" void kernel_launch(void* const* d_in, const int* in_sizes, int n_in,
                              void* d_out, int out_size, void* d_ws, size_t ws_size,
                              hipStream_t stream) {
    (void)in_sizes; (void)n_in; (void)out_size; (void)d_ws; (void)ws_size;
    ltc_kernel<<<256, 512, 0, stream>>>(
        (const float*)d_in[0], (const float*)d_in[1], (const float*)d_in[2],
        (const float*)d_in[3], (const float*)d_in[4], (const float*)d_in[5],
        (const float*)d_in[6], (const float*)d_in[7], (const float*)d_in[8],
        (float*)d_out);
}